// Round 3
// baseline (20829.224 us; speedup 1.0000x reference)
//
#include <hip/hip_runtime.h>
#include <math.h>

// AtomQueryFieldNet: NQ=4096, NA=512, pair MLP 18->64->64->32->1, cutoff mask,
// per-query 3-vector reduction, 3->64->3 head.
//
// R2: (a) all pair-MLP weights staged in LDS, read as float4 broadcasts
// (ds_read_b128, uniform addr across lanes, const offsets) — removes the R1
// s_load/SGPR serialization (VALUBusy 56%, 1471us). (b) cutoff compaction:
// only ~35% of pairs have dist<=6; build per-query in-range list, run MLP on
// listed atoms only, idle waves skip via wave-uniform branch. Exact (mask
// zeroes skipped terms).

#define TPB 256

// LDS float offsets (all /4 -> float4-aligned)
#define OW1 0      // (18,64)
#define OB1 1152   // (64)
#define OW2 1216   // (64,64)
#define OB2 5312   // (64)
#define OW3 5376   // (64,32)
#define OB3 7424   // (32)
#define OW4 7456   // (32)
#define OB4 7488   // (1)

__global__ __launch_bounds__(TPB, 1) void aqfn_kernel(
    const float* __restrict__ atom_pos,   // (512,3)
    const float* __restrict__ atom_feat,  // (512,2)
    const float* __restrict__ query_pos,  // (4096,3)
    const float* __restrict__ W1, const float* __restrict__ b1,
    const float* __restrict__ W2, const float* __restrict__ b2,
    const float* __restrict__ W3, const float* __restrict__ b3,
    const float* __restrict__ W4, const float* __restrict__ b4,
    const float* __restrict__ W5, const float* __restrict__ b5,
    const float* __restrict__ W6, const float* __restrict__ b6,
    float* __restrict__ out)              // (4096,3)
{
    __shared__ __align__(16) float w[7492];
    __shared__ __align__(16) float apos[1536];   // (512,3)
    __shared__ __align__(16) float afeat[1024];  // (512,2)
    __shared__ int alist[512];
    __shared__ int cnt;
    __shared__ float red[4][3];

    const int tid  = threadIdx.x;
    const int wave = tid >> 6;
    const int lane = tid & 63;

    // ---- stage weights + atoms into LDS (once per block) ----
    for (int i = tid; i < 1152; i += TPB) w[OW1+i] = W1[i];
    for (int i = tid; i < 64;   i += TPB) w[OB1+i] = b1[i];
    for (int i = tid; i < 4096; i += TPB) w[OW2+i] = W2[i];
    for (int i = tid; i < 64;   i += TPB) w[OB2+i] = b2[i];
    for (int i = tid; i < 2048; i += TPB) w[OW3+i] = W3[i];
    for (int i = tid; i < 32;   i += TPB) w[OB3+i] = b3[i];
    for (int i = tid; i < 32;   i += TPB) w[OW4+i] = W4[i];
    if (tid == 0) { w[OB4] = b4[0]; cnt = 0; }
    for (int i = tid; i < 1536; i += TPB) apos[i]  = atom_pos[i];
    for (int i = tid; i < 1024; i += TPB) afeat[i] = atom_feat[i];
    __syncthreads();

    const int q = blockIdx.x;
    const float qx = query_pos[q*3+0];
    const float qy = query_pos[q*3+1];
    const float qz = query_pos[q*3+2];

    // ---- compaction: indices of atoms with dist <= 6 ----
    for (int a = tid; a < 512; a += TPB) {
        const float rx = qx - apos[a*3+0];
        const float ry = qy - apos[a*3+1];
        const float rz = qz - apos[a*3+2];
        const float ex = __fadd_rn(rx, 1e-12f);
        const float ey = __fadd_rn(ry, 1e-12f);
        const float ez = __fadd_rn(rz, 1e-12f);
        const float dd = __fadd_rn(__fadd_rn(__fmul_rn(ex,ex), __fmul_rn(ey,ey)),
                                   __fmul_rn(ez,ez));
        const float dist = sqrtf(dd);
        if (dist <= 6.0f) { int p = atomicAdd(&cnt, 1); alist[p] = a; }
    }
    __syncthreads();
    const int count = cnt;

    const float4* wf4 = (const float4*)w;
    float wacc0 = 0.f, wacc1 = 0.f, wacc2 = 0.f;

    #pragma unroll 1
    for (int base = 0; base < count; base += TPB) {
        const int wave_first = base + (tid & ~63);
        if (wave_first < count) {              // wave-uniform: idle waves skip
            const int t = base + tid;
            const bool valid = (t < count);
            const int a = valid ? alist[t] : alist[0];

            const float rx = qx - apos[a*3+0];
            const float ry = qy - apos[a*3+1];
            const float rz = qz - apos[a*3+2];
            const float ex = __fadd_rn(rx, 1e-12f);
            const float ey = __fadd_rn(ry, 1e-12f);
            const float ez = __fadd_rn(rz, 1e-12f);
            const float dd = __fadd_rn(__fadd_rn(__fmul_rn(ex,ex), __fmul_rn(ey,ey)),
                                       __fmul_rn(ez,ez));
            const float dist = sqrtf(dd);
            const float f0 = afeat[a*2+0];
            const float f1 = afeat[a*2+1];

            // ---- layer 1: [f0,f1,rbf(16)](18) @ W1 + b1, relu ----
            float h1[64];
            #pragma unroll
            for (int j4 = 0; j4 < 16; ++j4) {
                const float4 wb = wf4[OB1/4 + j4];
                const float4 r0 = wf4[OW1/4 + 0*16 + j4];
                const float4 r1 = wf4[OW1/4 + 1*16 + j4];
                h1[j4*4+0] = fmaf(f0, r0.x, fmaf(f1, r1.x, wb.x));
                h1[j4*4+1] = fmaf(f0, r0.y, fmaf(f1, r1.y, wb.y));
                h1[j4*4+2] = fmaf(f0, r0.z, fmaf(f1, r1.z, wb.z));
                h1[j4*4+3] = fmaf(f0, r0.w, fmaf(f1, r1.w, wb.w));
            }
            #pragma unroll
            for (int c = 0; c < 16; ++c) {
                const float tt = dist - 0.4f * (float)c;  // centers linspace(0,6,16)
                const float xc = __expf(-10.0f * tt * tt);
                #pragma unroll
                for (int j4 = 0; j4 < 16; ++j4) {
                    const float4 ww = wf4[OW1/4 + (2+c)*16 + j4];
                    h1[j4*4+0] = fmaf(xc, ww.x, h1[j4*4+0]);
                    h1[j4*4+1] = fmaf(xc, ww.y, h1[j4*4+1]);
                    h1[j4*4+2] = fmaf(xc, ww.z, h1[j4*4+2]);
                    h1[j4*4+3] = fmaf(xc, ww.w, h1[j4*4+3]);
                }
            }
            #pragma unroll
            for (int j = 0; j < 64; ++j) h1[j] = fmaxf(h1[j], 0.f);

            // ---- layer 2: h1(64) @ W2(64,64) + b2, relu ----
            float h2[64];
            #pragma unroll
            for (int j4 = 0; j4 < 16; ++j4) {
                const float4 wb = wf4[OB2/4 + j4];
                h2[j4*4+0] = wb.x; h2[j4*4+1] = wb.y;
                h2[j4*4+2] = wb.z; h2[j4*4+3] = wb.w;
            }
            #pragma unroll
            for (int k = 0; k < 64; ++k) {
                const float hk = h1[k];
                #pragma unroll
                for (int j4 = 0; j4 < 16; ++j4) {
                    const float4 ww = wf4[OW2/4 + k*16 + j4];
                    h2[j4*4+0] = fmaf(hk, ww.x, h2[j4*4+0]);
                    h2[j4*4+1] = fmaf(hk, ww.y, h2[j4*4+1]);
                    h2[j4*4+2] = fmaf(hk, ww.z, h2[j4*4+2]);
                    h2[j4*4+3] = fmaf(hk, ww.w, h2[j4*4+3]);
                }
            }
            #pragma unroll
            for (int j = 0; j < 64; ++j) h2[j] = fmaxf(h2[j], 0.f);

            // ---- layer 3: h2 @ W3(64,32) + b3 ----
            float h3[32];
            #pragma unroll
            for (int m4 = 0; m4 < 8; ++m4) {
                const float4 wb = wf4[OB3/4 + m4];
                h3[m4*4+0] = wb.x; h3[m4*4+1] = wb.y;
                h3[m4*4+2] = wb.z; h3[m4*4+3] = wb.w;
            }
            #pragma unroll
            for (int k = 0; k < 64; ++k) {
                const float hk = h2[k];
                #pragma unroll
                for (int m4 = 0; m4 < 8; ++m4) {
                    const float4 ww = wf4[OW3/4 + k*8 + m4];
                    h3[m4*4+0] = fmaf(hk, ww.x, h3[m4*4+0]);
                    h3[m4*4+1] = fmaf(hk, ww.y, h3[m4*4+1]);
                    h3[m4*4+2] = fmaf(hk, ww.z, h3[m4*4+2]);
                    h3[m4*4+3] = fmaf(hk, ww.w, h3[m4*4+3]);
                }
            }

            // ---- layer 4: relu(h3)(32) @ W4 + b4 ----
            float s = w[OB4];
            #pragma unroll
            for (int m4 = 0; m4 < 8; ++m4) {
                const float4 ww = wf4[OW4/4 + m4];
                s = fmaf(fmaxf(h3[m4*4+0], 0.f), ww.x, s);
                s = fmaf(fmaxf(h3[m4*4+1], 0.f), ww.y, s);
                s = fmaf(fmaxf(h3[m4*4+2], 0.f), ww.z, s);
                s = fmaf(fmaxf(h3[m4*4+3], 0.f), ww.w, s);
            }

            const float inv = 1.0f / (dist + 1e-12f);
            const float wm  = (valid && dist <= 6.0f) ? (s * inv) : 0.f;
            wacc0 = fmaf(wm, rx, wacc0);
            wacc1 = fmaf(wm, ry, wacc1);
            wacc2 = fmaf(wm, rz, wacc2);
        }
    }

    // ---- wave reduce + cross-wave combine ----
    #pragma unroll
    for (int off = 32; off > 0; off >>= 1) {
        wacc0 += __shfl_down(wacc0, off);
        wacc1 += __shfl_down(wacc1, off);
        wacc2 += __shfl_down(wacc2, off);
    }
    if (lane == 0) {
        red[wave][0] = wacc0; red[wave][1] = wacc1; red[wave][2] = wacc2;
    }
    __syncthreads();

    // ---- head: 3 -> 64 -> 3, wave 0, lane = hidden unit ----
    if (wave == 0) {
        const float v0 = red[0][0] + red[1][0] + red[2][0] + red[3][0];
        const float v1 = red[0][1] + red[1][1] + red[2][1] + red[3][1];
        const float v2 = red[0][2] + red[1][2] + red[2][2] + red[3][2];
        float t = fmaf(v0, W5[lane],
                  fmaf(v1, W5[64+lane],
                  fmaf(v2, W5[128+lane], b5[lane])));
        t = fmaxf(t, 0.f);
        float o0 = t * W6[lane*3+0];
        float o1 = t * W6[lane*3+1];
        float o2 = t * W6[lane*3+2];
        #pragma unroll
        for (int off = 32; off > 0; off >>= 1) {
            o0 += __shfl_down(o0, off);
            o1 += __shfl_down(o1, off);
            o2 += __shfl_down(o2, off);
        }
        if (lane == 0) {
            out[q*3+0] = o0 + b6[0];
            out[q*3+1] = o1 + b6[1];
            out[q*3+2] = o2 + b6[2];
        }
    }
}

extern "C" void kernel_launch(void* const* d_in, const int* in_sizes, int n_in,
                              void* d_out, int out_size, void* d_ws, size_t ws_size,
                              hipStream_t stream) {
    const float* atom_pos  = (const float*)d_in[0];
    const float* atom_feat = (const float*)d_in[1];
    const float* query_pos = (const float*)d_in[2];
    const float* W1 = (const float*)d_in[3];  const float* b1 = (const float*)d_in[4];
    const float* W2 = (const float*)d_in[5];  const float* b2 = (const float*)d_in[6];
    const float* W3 = (const float*)d_in[7];  const float* b3 = (const float*)d_in[8];
    const float* W4 = (const float*)d_in[9];  const float* b4 = (const float*)d_in[10];
    const float* W5 = (const float*)d_in[11]; const float* b5 = (const float*)d_in[12];
    const float* W6 = (const float*)d_in[13]; const float* b6 = (const float*)d_in[14];
    float* out = (float*)d_out;

    dim3 grid(4096), block(TPB);
    hipLaunchKernelGGL(aqfn_kernel, grid, block, 0, stream,
                       atom_pos, atom_feat, query_pos,
                       W1,b1,W2,b2,W3,b3,W4,b4,W5,b5,W6,b6, out);
}

// Round 4
// 389.231 us; speedup vs baseline: 53.5137x; 53.5137x over previous
//
#include <hip/hip_runtime.h>
#include <math.h>

// AtomQueryFieldNet: NQ=4096, NA=512, pair MLP 18->64->64->32->1, cutoff mask,
// per-query 3-vector reduction, 3->64->3 head.
//
// R4: thread = (pair, half). Each thread computes 32 of 64 hidden units.
//  - Weights via wave-uniform s_load (SGPR path, zero VGPR cost). Half-width
//    rows (32 SGPRs) let the compiler double-buffer within the ~102-SGPR
//    budget, fixing R1's 56%-VALUBusy SMEM serialization.
//  - Activation liveness <= ~96 VGPRs -> no scratch demotion (R3 failure mode:
//    >256 addressable VGPRs -> arrays demoted, 40GB scratch traffic).
//  - Halves exchange h1/h2 via transposed LDS hbuf[h][pair] (conflict-free b32).
//  - Cutoff compaction (~35% of pairs survive dist<=6), (rel,dist) cached as
//    float4 at compaction time.

#define TPB 256

__global__ __launch_bounds__(TPB, 1) void aqfn_kernel(
    const float* __restrict__ atom_pos,   // (512,3)
    const float* __restrict__ atom_feat,  // (512,2)
    const float* __restrict__ query_pos,  // (4096,3)
    const float* __restrict__ W1, const float* __restrict__ b1,  // (18,64),(64)
    const float* __restrict__ W2, const float* __restrict__ b2,  // (64,64),(64)
    const float* __restrict__ W3, const float* __restrict__ b3,  // (64,32),(32)
    const float* __restrict__ W4, const float* __restrict__ b4,  // (32,1),(1)
    const float* __restrict__ W5, const float* __restrict__ b5,  // (3,64),(64)
    const float* __restrict__ W6, const float* __restrict__ b6,  // (64,3),(3)
    float* __restrict__ out)              // (4096,3)
{
    __shared__ float4 rbuf[512];       // (rx,ry,rz,dist) of in-range atoms
    __shared__ int    ibuf[512];       // atom index of in-range atoms
    __shared__ float  hbuf[64][128];   // transposed exchange: [h-index][pair]
    __shared__ float  sbuf[2][128];    // per-half layer-4 partials
    __shared__ float  red[2][3];
    __shared__ int    cnt;

    const int tid  = threadIdx.x;
    const int p    = tid & 127;                                   // pair slot
    const int half = __builtin_amdgcn_readfirstlane(tid >> 7);    // wave-uniform
    const int jb   = half * 32;    // this half's h1/h2 column base
    const int ob   = 32 - jb;      // other half's base
    const int mb   = half * 16;    // this half's h3 base
    const int wave = tid >> 6;
    const int lane = tid & 63;
    const int wp0  = __builtin_amdgcn_readfirstlane(p & ~63);     // wave's first pair

    if (tid == 0) cnt = 0;
    __syncthreads();

    const int q = blockIdx.x;
    const float qx = query_pos[q*3+0];
    const float qy = query_pos[q*3+1];
    const float qz = query_pos[q*3+2];

    // ---- compaction: atoms with dist <= 6, cache (rel, dist) ----
    for (int a = tid; a < 512; a += TPB) {
        const float rx = qx - atom_pos[a*3+0];
        const float ry = qy - atom_pos[a*3+1];
        const float rz = qz - atom_pos[a*3+2];
        const float ex = __fadd_rn(rx, 1e-12f);
        const float ey = __fadd_rn(ry, 1e-12f);
        const float ez = __fadd_rn(rz, 1e-12f);
        const float dd = __fadd_rn(__fadd_rn(__fmul_rn(ex,ex), __fmul_rn(ey,ey)),
                                   __fmul_rn(ez,ez));
        const float dist = sqrtf(dd);
        if (dist <= 6.0f) {
            const int s = atomicAdd(&cnt, 1);
            rbuf[s] = make_float4(rx, ry, rz, dist);
            ibuf[s] = a;
        }
    }
    __syncthreads();
    const int count = cnt;

    float wacc0 = 0.f, wacc1 = 0.f, wacc2 = 0.f;

    #pragma unroll 1
    for (int base = 0; base < count; base += 128) {
        const bool wactive = (base + wp0) < count;   // wave-uniform skip
        const int  t     = base + p;
        const bool valid = (t < count);
        const int  ts    = valid ? t : 0;

        float rx = 0.f, ry = 0.f, rz = 0.f, dist = 0.f;
        float h1o[32];
        float h2o[32];

        // ---- layer 1 (own 32 columns) ----
        if (wactive) {
            const float4 r = rbuf[ts];
            rx = r.x; ry = r.y; rz = r.z; dist = r.w;
            const int a = ibuf[ts];
            const float f0 = atom_feat[a*2+0];
            const float f1 = atom_feat[a*2+1];

            #pragma unroll
            for (int jj = 0; jj < 32; ++jj)
                h1o[jj] = fmaf(f0, W1[jb+jj], fmaf(f1, W1[64+jb+jj], b1[jb+jj]));
            #pragma unroll
            for (int c = 0; c < 16; ++c) {
                const float tt = dist - 0.4f * (float)c;   // centers linspace(0,6,16)
                const float xc = __expf(-10.0f * tt * tt);
                const float* wr = &W1[(2+c)*64 + jb];
                #pragma unroll
                for (int jj = 0; jj < 32; ++jj)
                    h1o[jj] = fmaf(xc, wr[jj], h1o[jj]);
            }
            #pragma unroll
            for (int jj = 0; jj < 32; ++jj) {
                h1o[jj] = fmaxf(h1o[jj], 0.f);
                hbuf[jb+jj][p] = h1o[jj];
            }
        }
        __syncthreads();   // A: h1 halves published

        // ---- layer 2 (own 32 columns, full 64-k) ----
        if (wactive) {
            float h1x[32];
            #pragma unroll
            for (int kk = 0; kk < 32; ++kk) h1x[kk] = hbuf[ob+kk][p];

            #pragma unroll
            for (int jj = 0; jj < 32; ++jj) h2o[jj] = b2[jb+jj];
            #pragma unroll
            for (int kk = 0; kk < 32; ++kk) {
                const float hk = h1o[kk];
                const float* wr = &W2[(jb+kk)*64 + jb];
                #pragma unroll
                for (int jj = 0; jj < 32; ++jj)
                    h2o[jj] = fmaf(hk, wr[jj], h2o[jj]);
            }
            #pragma unroll
            for (int kk = 0; kk < 32; ++kk) {
                const float hk = h1x[kk];
                const float* wr = &W2[(ob+kk)*64 + jb];
                #pragma unroll
                for (int jj = 0; jj < 32; ++jj)
                    h2o[jj] = fmaf(hk, wr[jj], h2o[jj]);
            }
            #pragma unroll
            for (int jj = 0; jj < 32; ++jj) h2o[jj] = fmaxf(h2o[jj], 0.f);
        }
        __syncthreads();   // B: all h1 reads done -> hbuf reusable

        if (wactive) {
            #pragma unroll
            for (int jj = 0; jj < 32; ++jj) hbuf[jb+jj][p] = h2o[jj];
        }
        __syncthreads();   // C: h2 halves published

        // ---- layer 3 (own 16 outputs) + layer 4 partial ----
        if (wactive) {
            float h2x[32];
            #pragma unroll
            for (int kk = 0; kk < 32; ++kk) h2x[kk] = hbuf[ob+kk][p];

            float h3[16];
            #pragma unroll
            for (int mm = 0; mm < 16; ++mm) h3[mm] = b3[mb+mm];
            #pragma unroll
            for (int kk = 0; kk < 32; ++kk) {
                const float hk = h2o[kk];
                const float* wr = &W3[(jb+kk)*32 + mb];
                #pragma unroll
                for (int mm = 0; mm < 16; ++mm)
                    h3[mm] = fmaf(hk, wr[mm], h3[mm]);
            }
            #pragma unroll
            for (int kk = 0; kk < 32; ++kk) {
                const float hk = h2x[kk];
                const float* wr = &W3[(ob+kk)*32 + mb];
                #pragma unroll
                for (int mm = 0; mm < 16; ++mm)
                    h3[mm] = fmaf(hk, wr[mm], h3[mm]);
            }
            float s = (half == 0) ? b4[0] : 0.f;
            #pragma unroll
            for (int mm = 0; mm < 16; ++mm)
                s = fmaf(fmaxf(h3[mm], 0.f), W4[mb+mm], s);
            sbuf[half][p] = s;
        }
        __syncthreads();   // D: partials published

        // ---- per-pair weighted accumulation (half 0 only) ----
        if (wactive && half == 0) {
            const float stot = sbuf[0][p] + sbuf[1][p];
            const float inv  = 1.0f / (dist + 1e-12f);
            const float wm   = valid ? (stot * inv) : 0.f;
            wacc0 = fmaf(wm, rx, wacc0);
            wacc1 = fmaf(wm, ry, wacc1);
            wacc2 = fmaf(wm, rz, wacc2);
        }
        __syncthreads();   // E: sbuf/hbuf safe for next chunk
    }

    // ---- reduce wacc over waves 0,1 (half-0 threads) ----
    #pragma unroll
    for (int off = 32; off > 0; off >>= 1) {
        wacc0 += __shfl_down(wacc0, off);
        wacc1 += __shfl_down(wacc1, off);
        wacc2 += __shfl_down(wacc2, off);
    }
    if (half == 0 && lane == 0) {
        red[wave][0] = wacc0; red[wave][1] = wacc1; red[wave][2] = wacc2;
    }
    __syncthreads();

    // ---- head: 3 -> 64 -> 3 (wave 0, lane = hidden unit) ----
    if (wave == 0) {
        const float v0 = red[0][0] + red[1][0];
        const float v1 = red[0][1] + red[1][1];
        const float v2 = red[0][2] + red[1][2];
        float th = fmaf(v0, W5[lane],
                   fmaf(v1, W5[64+lane],
                   fmaf(v2, W5[128+lane], b5[lane])));
        th = fmaxf(th, 0.f);
        float o0 = th * W6[lane*3+0];
        float o1 = th * W6[lane*3+1];
        float o2 = th * W6[lane*3+2];
        #pragma unroll
        for (int off = 32; off > 0; off >>= 1) {
            o0 += __shfl_down(o0, off);
            o1 += __shfl_down(o1, off);
            o2 += __shfl_down(o2, off);
        }
        if (lane == 0) {
            out[q*3+0] = o0 + b6[0];
            out[q*3+1] = o1 + b6[1];
            out[q*3+2] = o2 + b6[2];
        }
    }
}

extern "C" void kernel_launch(void* const* d_in, const int* in_sizes, int n_in,
                              void* d_out, int out_size, void* d_ws, size_t ws_size,
                              hipStream_t stream) {
    const float* atom_pos  = (const float*)d_in[0];
    const float* atom_feat = (const float*)d_in[1];
    const float* query_pos = (const float*)d_in[2];
    const float* W1 = (const float*)d_in[3];  const float* b1 = (const float*)d_in[4];
    const float* W2 = (const float*)d_in[5];  const float* b2 = (const float*)d_in[6];
    const float* W3 = (const float*)d_in[7];  const float* b3 = (const float*)d_in[8];
    const float* W4 = (const float*)d_in[9];  const float* b4 = (const float*)d_in[10];
    const float* W5 = (const float*)d_in[11]; const float* b5 = (const float*)d_in[12];
    const float* W6 = (const float*)d_in[13]; const float* b6 = (const float*)d_in[14];
    float* out = (float*)d_out;

    dim3 grid(4096), block(TPB);
    hipLaunchKernelGGL(aqfn_kernel, grid, block, 0, stream,
                       atom_pos, atom_feat, query_pos,
                       W1,b1,W2,b2,W3,b3,W4,b4,W5,b5,W6,b6, out);
}

// Round 5
// 154.376 us; speedup vs baseline: 134.9252x; 2.5213x over previous
//
#include <hip/hip_runtime.h>
#include <math.h>

// AtomQueryFieldNet: NQ=4096, NA=512, pair MLP 18->64->64->32->1, cutoff mask,
// per-query 3-vector reduction, 3->64->3 head.
//
// R5: MFMA (fp16 in, fp32 accum) for the pair MLP.
//  - Tile = 16 pairs. L1: 4x mfma_16x16x32_f16 (K=32 covers 18 inputs, rest 0);
//    L2: 8x; L3: 4x. L4 (32->1) in VALU via shfl_xor reduce.
//  - C-layout -> A-layout between layers via per-wave private LDS exchange
//    (pitch 72 f16: ds_read_b128 aligned). NO __syncthreads in tile loop.
//  - fp16 not bf16: 8x mantissa headroom (bf16 random-walk over ~180 pairs
//    estimated too close to the 7.1e-2 threshold). dist/rel/mask/reductions fp32.
//  - Cutoff compaction (R4): ~35% of pairs survive dist<=6.
//  - QB=2 queries/block amortizes per-wave weight-fragment preload.

typedef _Float16 f16x8 __attribute__((ext_vector_type(8)));
typedef float    f32x4 __attribute__((ext_vector_type(4)));

#define TPB 256
#define QB  2
#define XP  72   // exchange row pitch in f16 units (144 B, 16B-aligned rows)

__global__ __launch_bounds__(TPB, 1) void aqfn_kernel(
    const float* __restrict__ atom_pos,   // (512,3)
    const float* __restrict__ atom_feat,  // (512,2)
    const float* __restrict__ query_pos,  // (4096,3)
    const float* __restrict__ W1, const float* __restrict__ b1,  // (18,64),(64)
    const float* __restrict__ W2, const float* __restrict__ b2,  // (64,64),(64)
    const float* __restrict__ W3, const float* __restrict__ b3,  // (64,32),(32)
    const float* __restrict__ W4, const float* __restrict__ b4,  // (32,1),(1)
    const float* __restrict__ W5, const float* __restrict__ b5,  // (3,64),(64)
    const float* __restrict__ W6, const float* __restrict__ b6,  // (64,3),(3)
    float* __restrict__ out)              // (4096,3)
{
    __shared__ float4 rbuf[512];                      // (rx,ry,rz,dist)
    __shared__ float2 fbuf[512];                      // (f0,f1)
    __shared__ float  sbuf[512];                      // per-pair scalar s
    __shared__ __align__(16) _Float16 exch[4][16*XP]; // per-wave exchange
    __shared__ float  red[4][3];
    __shared__ int    cnt;

    const int tid  = threadIdx.x;
    const int wave = tid >> 6;
    const int lane = tid & 63;
    const int col  = lane & 15;
    const int quad = lane >> 4;

    // ---- per-wave weight fragment preload (once per block) ----
    // B-frag layout: B[k][n]: n = col, k = quad*8 + j
    f16x8 w1f[4], w2f[2][4], w3f[2][2];
    #pragma unroll
    for (int nt = 0; nt < 4; ++nt)
        #pragma unroll
        for (int j = 0; j < 8; ++j) {
            const int k = quad*8 + j;
            w1f[nt][j] = (k < 18) ? (_Float16)W1[k*64 + nt*16 + col] : (_Float16)0.0f;
        }
    #pragma unroll
    for (int kc = 0; kc < 2; ++kc)
        #pragma unroll
        for (int nt = 0; nt < 4; ++nt)
            #pragma unroll
            for (int j = 0; j < 8; ++j)
                w2f[kc][nt][j] = (_Float16)W2[(kc*32 + quad*8 + j)*64 + nt*16 + col];
    #pragma unroll
    for (int kc = 0; kc < 2; ++kc)
        #pragma unroll
        for (int nt = 0; nt < 2; ++nt)
            #pragma unroll
            for (int j = 0; j < 8; ++j)
                w3f[kc][nt][j] = (_Float16)W3[(kc*32 + quad*8 + j)*32 + nt*16 + col];

    float b1f[4], b2f[4], b3f[2];
    #pragma unroll
    for (int nt = 0; nt < 4; ++nt) { b1f[nt] = b1[nt*16+col]; b2f[nt] = b2[nt*16+col]; }
    b3f[0] = b3[col]; b3f[1] = b3[16+col];
    const float w4a = W4[col], w4b = W4[16+col], b4v = b4[0];
    _Float16* __restrict__ myex = &exch[wave][0];

    #pragma unroll 1
    for (int qi = 0; qi < QB; ++qi) {
        const int q = blockIdx.x * QB + qi;
        __syncthreads();                    // previous iteration's readers done
        if (tid == 0) cnt = 0;
        __syncthreads();

        const float qx = query_pos[q*3+0];
        const float qy = query_pos[q*3+1];
        const float qz = query_pos[q*3+2];

        // ---- compaction: atoms with dist <= 6 ----
        for (int a = tid; a < 512; a += TPB) {
            const float rx = qx - atom_pos[a*3+0];
            const float ry = qy - atom_pos[a*3+1];
            const float rz = qz - atom_pos[a*3+2];
            const float ex = __fadd_rn(rx, 1e-12f);
            const float ey = __fadd_rn(ry, 1e-12f);
            const float ez = __fadd_rn(rz, 1e-12f);
            const float dd = __fadd_rn(__fadd_rn(__fmul_rn(ex,ex), __fmul_rn(ey,ey)),
                                       __fmul_rn(ez,ez));
            const float dist = sqrtf(dd);
            if (dist <= 6.0f) {
                const int s = atomicAdd(&cnt, 1);
                rbuf[s] = make_float4(rx, ry, rz, dist);
                fbuf[s] = make_float2(atom_feat[a*2+0], atom_feat[a*2+1]);
            }
        }
        __syncthreads();
        const int count  = cnt;
        const int ntiles = (count + 15) >> 4;

        // ---- tile loop: 16 pairs per tile, one wave per tile, no barriers ----
        #pragma unroll 1
        for (int tile = wave; tile < ntiles; tile += 4) {
            const int row0 = tile << 4;
            int pr = row0 + col; if (pr >= count) pr = count - 1;
            const float4 r  = rbuf[pr];
            const float2 ff = fbuf[pr];
            const float dist = r.w;

            // X A-frag: A[m=col][k=quad*8+j]; x = [f0,f1,rbf(16),0...]
            f16x8 xa;
            #pragma unroll
            for (int j = 0; j < 8; ++j) {
                const int k = quad*8 + j;
                const float tt = dist - 0.4f * (float)(k - 2);
                float v = __expf(-10.0f * tt * tt);
                v = (k < 18) ? v : 0.0f;
                if (j == 0) v = (quad == 0) ? ff.x : v;
                if (j == 1) v = (quad == 0) ? ff.y : v;
                xa[j] = (_Float16)v;
            }

            // ---- L1: 4 N-tiles, K=32 ----
            #pragma unroll
            for (int nt = 0; nt < 4; ++nt) {
                f32x4 c = {b1f[nt], b1f[nt], b1f[nt], b1f[nt]};
                c = __builtin_amdgcn_mfma_f32_16x16x32_f16(xa, w1f[nt], c, 0, 0, 0);
                #pragma unroll
                for (int rr = 0; rr < 4; ++rr)
                    myex[(quad*4+rr)*XP + nt*16 + col] = (_Float16)fmaxf(c[rr], 0.0f);
            }
            // read back as A-frags (row = col, k contiguous)
            f16x8 a2[2];
            #pragma unroll
            for (int kc = 0; kc < 2; ++kc)
                a2[kc] = *(const f16x8*)&myex[col*XP + kc*32 + quad*8];

            // ---- L2: 4 N-tiles x 2 K-chunks ----
            #pragma unroll
            for (int nt = 0; nt < 4; ++nt) {
                f32x4 c = {b2f[nt], b2f[nt], b2f[nt], b2f[nt]};
                c = __builtin_amdgcn_mfma_f32_16x16x32_f16(a2[0], w2f[0][nt], c, 0, 0, 0);
                c = __builtin_amdgcn_mfma_f32_16x16x32_f16(a2[1], w2f[1][nt], c, 0, 0, 0);
                #pragma unroll
                for (int rr = 0; rr < 4; ++rr)
                    myex[(quad*4+rr)*XP + nt*16 + col] = (_Float16)fmaxf(c[rr], 0.0f);
            }
            f16x8 a3[2];
            #pragma unroll
            for (int kc = 0; kc < 2; ++kc)
                a3[kc] = *(const f16x8*)&myex[col*XP + kc*32 + quad*8];

            // ---- L3: 2 N-tiles x 2 K-chunks ----
            f32x4 h3[2];
            #pragma unroll
            for (int nt = 0; nt < 2; ++nt) {
                f32x4 c = {b3f[nt], b3f[nt], b3f[nt], b3f[nt]};
                c = __builtin_amdgcn_mfma_f32_16x16x32_f16(a3[0], w3f[0][nt], c, 0, 0, 0);
                h3[nt] = __builtin_amdgcn_mfma_f32_16x16x32_f16(a3[1], w3f[1][nt], c, 0, 0, 0);
            }

            // ---- L4: s[row] = sum_col relu(h3)*W4 ; reduce over 16 cols ----
            float t[4];
            #pragma unroll
            for (int rr = 0; rr < 4; ++rr)
                t[rr] = fmaxf(h3[0][rr], 0.0f) * w4a + fmaxf(h3[1][rr], 0.0f) * w4b;
            #pragma unroll
            for (int off = 1; off < 16; off <<= 1) {
                #pragma unroll
                for (int rr = 0; rr < 4; ++rr)
                    t[rr] += __shfl_xor(t[rr], off);
            }
            if (col == 0) {
                #pragma unroll
                for (int rr = 0; rr < 4; ++rr) {
                    const int pr2 = row0 + quad*4 + rr;
                    if (pr2 < count) sbuf[pr2] = t[rr] + b4v;
                }
            }
        }
        __syncthreads();

        // ---- weighted accumulation (fp32) ----
        float wacc0 = 0.f, wacc1 = 0.f, wacc2 = 0.f;
        for (int tp = tid; tp < count; tp += TPB) {
            const float4 rr = rbuf[tp];
            const float  s  = sbuf[tp];
            const float  wm = s * (1.0f / (rr.w + 1e-12f));
            wacc0 = fmaf(wm, rr.x, wacc0);
            wacc1 = fmaf(wm, rr.y, wacc1);
            wacc2 = fmaf(wm, rr.z, wacc2);
        }
        #pragma unroll
        for (int off = 32; off > 0; off >>= 1) {
            wacc0 += __shfl_down(wacc0, off);
            wacc1 += __shfl_down(wacc1, off);
            wacc2 += __shfl_down(wacc2, off);
        }
        if (lane == 0) { red[wave][0] = wacc0; red[wave][1] = wacc1; red[wave][2] = wacc2; }
        __syncthreads();

        // ---- head: 3 -> 64 -> 3 (wave 0, lane = hidden unit) ----
        if (wave == 0) {
            const float v0 = red[0][0] + red[1][0] + red[2][0] + red[3][0];
            const float v1 = red[0][1] + red[1][1] + red[2][1] + red[3][1];
            const float v2 = red[0][2] + red[1][2] + red[2][2] + red[3][2];
            float th = fmaf(v0, W5[lane],
                       fmaf(v1, W5[64+lane],
                       fmaf(v2, W5[128+lane], b5[lane])));
            th = fmaxf(th, 0.f);
            float o0 = th * W6[lane*3+0];
            float o1 = th * W6[lane*3+1];
            float o2 = th * W6[lane*3+2];
            #pragma unroll
            for (int off = 32; off > 0; off >>= 1) {
                o0 += __shfl_down(o0, off);
                o1 += __shfl_down(o1, off);
                o2 += __shfl_down(o2, off);
            }
            if (lane == 0) {
                out[q*3+0] = o0 + b6[0];
                out[q*3+1] = o1 + b6[1];
                out[q*3+2] = o2 + b6[2];
            }
        }
    }
}

extern "C" void kernel_launch(void* const* d_in, const int* in_sizes, int n_in,
                              void* d_out, int out_size, void* d_ws, size_t ws_size,
                              hipStream_t stream) {
    const float* atom_pos  = (const float*)d_in[0];
    const float* atom_feat = (const float*)d_in[1];
    const float* query_pos = (const float*)d_in[2];
    const float* W1 = (const float*)d_in[3];  const float* b1 = (const float*)d_in[4];
    const float* W2 = (const float*)d_in[5];  const float* b2 = (const float*)d_in[6];
    const float* W3 = (const float*)d_in[7];  const float* b3 = (const float*)d_in[8];
    const float* W4 = (const float*)d_in[9];  const float* b4 = (const float*)d_in[10];
    const float* W5 = (const float*)d_in[11]; const float* b5 = (const float*)d_in[12];
    const float* W6 = (const float*)d_in[13]; const float* b6 = (const float*)d_in[14];
    float* out = (float*)d_out;

    dim3 grid(4096 / QB), block(TPB);
    hipLaunchKernelGGL(aqfn_kernel, grid, block, 0, stream,
                       atom_pos, atom_feat, query_pos,
                       W1,b1,W2,b2,W3,b3,W4,b4,W5,b5,W6,b6, out);
}

// Round 6
// 153.498 us; speedup vs baseline: 135.6968x; 1.0057x over previous
//
#include <hip/hip_runtime.h>
#include <math.h>

// AtomQueryFieldNet: NQ=4096, NA=512, pair MLP 18->64->64->32->1, cutoff mask,
// per-query 3-vector reduction, 3->64->3 head.
//
// R6: wave = query, ZERO barriers.
//  - R5 was latency-bound (MfmaUtil 4.7%, VALUBusy 32%, occ 18%): one long
//    dependent chain per tile, too few resident waves to overlap.
//  - Each wave owns one query: ballot/prefix compaction (no LDS atomics, no
//    __syncthreads), per-wave private exchange, weighted accumulation fused
//    into the tile loop (col==0 lanes), head on the same wave.
//  - grid 1024 x 4 waves; LDS ~40KB -> 4 blocks/CU; __launch_bounds__(256,4)
//    caps VGPR at 128 (R5 needed 100) -> 16 waves/CU, 4 chains/SIMD.
//  - MFMA math identical to R5 (fp16 in, fp32 accum; absmax 0.0156 vs 0.0712).

typedef _Float16 f16x8 __attribute__((ext_vector_type(8)));
typedef _Float16 f16x2 __attribute__((ext_vector_type(2)));
typedef float    f32x4 __attribute__((ext_vector_type(4)));

#define TPB 256
#define WPB 4     // waves (= queries) per block
#define CAP 384   // max in-range atoms per query (geometric max ~270)
#define XP  72    // exchange row pitch in f16 (144B rows, 16B-aligned)

__global__ __launch_bounds__(TPB, 4) void aqfn_kernel(
    const float* __restrict__ atom_pos,   // (512,3)
    const float* __restrict__ atom_feat,  // (512,2)
    const float* __restrict__ query_pos,  // (4096,3)
    const float* __restrict__ W1, const float* __restrict__ b1,  // (18,64),(64)
    const float* __restrict__ W2, const float* __restrict__ b2,  // (64,64),(64)
    const float* __restrict__ W3, const float* __restrict__ b3,  // (64,32),(32)
    const float* __restrict__ W4, const float* __restrict__ b4,  // (32,1),(1)
    const float* __restrict__ W5, const float* __restrict__ b5,  // (3,64),(64)
    const float* __restrict__ W6, const float* __restrict__ b6,  // (64,3),(3)
    float* __restrict__ out)              // (4096,3)
{
    __shared__ __align__(16) float4   rbuf[WPB][CAP];    // (rx,ry,rz,dist)
    __shared__ __align__(16) f16x2    fbuf[WPB][CAP];    // (f0,f1) as f16
    __shared__ __align__(16) _Float16 exch[WPB][16*XP];  // per-wave exchange

    const int tid  = threadIdx.x;
    const int wave = __builtin_amdgcn_readfirstlane(tid >> 6);
    const int lane = tid & 63;
    const int col  = lane & 15;
    const int quad = lane >> 4;
    const int q    = blockIdx.x * WPB + wave;            // wave-uniform

    // ---- per-wave weight fragment preload ----
    // B-frag layout: B[k][n]: n = col, k = quad*8 + j
    f16x8 w1f[4], w2f[2][4], w3f[2][2];
    #pragma unroll
    for (int nt = 0; nt < 4; ++nt)
        #pragma unroll
        for (int j = 0; j < 8; ++j) {
            const int k = quad*8 + j;
            w1f[nt][j] = (k < 18) ? (_Float16)W1[k*64 + nt*16 + col] : (_Float16)0.0f;
        }
    #pragma unroll
    for (int kc = 0; kc < 2; ++kc)
        #pragma unroll
        for (int nt = 0; nt < 4; ++nt)
            #pragma unroll
            for (int j = 0; j < 8; ++j)
                w2f[kc][nt][j] = (_Float16)W2[(kc*32 + quad*8 + j)*64 + nt*16 + col];
    #pragma unroll
    for (int kc = 0; kc < 2; ++kc)
        #pragma unroll
        for (int nt = 0; nt < 2; ++nt)
            #pragma unroll
            for (int j = 0; j < 8; ++j)
                w3f[kc][nt][j] = (_Float16)W3[(kc*32 + quad*8 + j)*32 + nt*16 + col];

    float b1f[4], b2f[4], b3f[2];
    #pragma unroll
    for (int nt = 0; nt < 4; ++nt) { b1f[nt] = b1[nt*16+col]; b2f[nt] = b2[nt*16+col]; }
    b3f[0] = b3[col]; b3f[1] = b3[16+col];
    const float w4a = W4[col], w4b = W4[16+col], b4v = b4[0];

    float4*    __restrict__ rb   = &rbuf[wave][0];
    f16x2*     __restrict__ fb   = &fbuf[wave][0];
    _Float16*  __restrict__ myex = &exch[wave][0];

    const float qx = query_pos[q*3+0];
    const float qy = query_pos[q*3+1];
    const float qz = query_pos[q*3+2];

    // ---- per-wave ballot compaction: atoms with dist <= 6 ----
    int count = 0;
    #pragma unroll 1
    for (int it = 0; it < 8; ++it) {
        const int a = it*64 + lane;
        const float rx = qx - atom_pos[a*3+0];
        const float ry = qy - atom_pos[a*3+1];
        const float rz = qz - atom_pos[a*3+2];
        const float ex = __fadd_rn(rx, 1e-12f);
        const float ey = __fadd_rn(ry, 1e-12f);
        const float ez = __fadd_rn(rz, 1e-12f);
        const float dd = __fadd_rn(__fadd_rn(__fmul_rn(ex,ex), __fmul_rn(ey,ey)),
                                   __fmul_rn(ez,ez));
        const float dist = sqrtf(dd);
        const bool  in   = (dist <= 6.0f);
        const unsigned long long m = __ballot(in);
        const int p = count + (int)__popcll(m & ((1ull << lane) - 1ull));
        if (in && p < CAP) {
            rb[p] = make_float4(rx, ry, rz, dist);
            fb[p] = f16x2{(_Float16)atom_feat[a*2+0], (_Float16)atom_feat[a*2+1]};
        }
        count += (int)__popcll(m);
    }
    if (count > CAP) count = CAP;   // unreachable (geometric max ~270)

    // ---- tile loop: 16 pairs/tile, one wave, no barriers ----
    float wacc0 = 0.f, wacc1 = 0.f, wacc2 = 0.f;
    const int ntiles = (count + 15) >> 4;

    #pragma unroll 1
    for (int tile = 0; tile < ntiles; ++tile) {
        const int row0 = tile << 4;
        int pr = row0 + col; if (pr >= count) pr = count - 1;
        const float4 r  = rb[pr];
        const f16x2  ff = fb[pr];
        const float dist = r.w;

        // X A-frag: A[m=col][k=quad*8+j]; x = [f0,f1,rbf(16),0...]
        f16x8 xa;
        #pragma unroll
        for (int j = 0; j < 8; ++j) {
            const int k = quad*8 + j;
            const float tt = dist - 0.4f * (float)(k - 2);   // centers linspace(0,6,16)
            float v = __expf(-10.0f * tt * tt);
            v = (k < 18) ? v : 0.0f;
            _Float16 xv = (_Float16)v;
            if (j == 0) xv = (quad == 0) ? ff[0] : xv;
            if (j == 1) xv = (quad == 0) ? ff[1] : xv;
            xa[j] = xv;
        }

        // ---- L1: 4 N-tiles, K=32 ----
        #pragma unroll
        for (int nt = 0; nt < 4; ++nt) {
            f32x4 c = {b1f[nt], b1f[nt], b1f[nt], b1f[nt]};
            c = __builtin_amdgcn_mfma_f32_16x16x32_f16(xa, w1f[nt], c, 0, 0, 0);
            #pragma unroll
            for (int rr = 0; rr < 4; ++rr)
                myex[(quad*4+rr)*XP + nt*16 + col] = (_Float16)fmaxf(c[rr], 0.0f);
        }
        f16x8 a2[2];
        #pragma unroll
        for (int kc = 0; kc < 2; ++kc)
            a2[kc] = *(const f16x8*)&myex[col*XP + kc*32 + quad*8];

        // ---- L2: 4 N-tiles x 2 K-chunks ----
        #pragma unroll
        for (int nt = 0; nt < 4; ++nt) {
            f32x4 c = {b2f[nt], b2f[nt], b2f[nt], b2f[nt]};
            c = __builtin_amdgcn_mfma_f32_16x16x32_f16(a2[0], w2f[0][nt], c, 0, 0, 0);
            c = __builtin_amdgcn_mfma_f32_16x16x32_f16(a2[1], w2f[1][nt], c, 0, 0, 0);
            #pragma unroll
            for (int rr = 0; rr < 4; ++rr)
                myex[(quad*4+rr)*XP + nt*16 + col] = (_Float16)fmaxf(c[rr], 0.0f);
        }
        f16x8 a3[2];
        #pragma unroll
        for (int kc = 0; kc < 2; ++kc)
            a3[kc] = *(const f16x8*)&myex[col*XP + kc*32 + quad*8];

        // ---- L3: 2 N-tiles x 2 K-chunks ----
        f32x4 h3[2];
        #pragma unroll
        for (int nt = 0; nt < 2; ++nt) {
            f32x4 c = {b3f[nt], b3f[nt], b3f[nt], b3f[nt]};
            c = __builtin_amdgcn_mfma_f32_16x16x32_f16(a3[0], w3f[0][nt], c, 0, 0, 0);
            h3[nt] = __builtin_amdgcn_mfma_f32_16x16x32_f16(a3[1], w3f[1][nt], c, 0, 0, 0);
        }

        // ---- L4: s[row] = sum over 32 h3 cols of relu(h3)*W4 ----
        float t[4];
        #pragma unroll
        for (int rr = 0; rr < 4; ++rr)
            t[rr] = fmaxf(h3[0][rr], 0.0f) * w4a + fmaxf(h3[1][rr], 0.0f) * w4b;
        #pragma unroll
        for (int off = 1; off < 16; off <<= 1) {
            #pragma unroll
            for (int rr = 0; rr < 4; ++rr)
                t[rr] += __shfl_xor(t[rr], off);
        }

        // ---- fused weighted accumulation: col==0 lanes own 4 pairs each ----
        if (col == 0) {
            #pragma unroll
            for (int rr = 0; rr < 4; ++rr) {
                const int p2 = row0 + quad*4 + rr;
                if (p2 < count) {
                    const float4 rv = rb[p2];
                    const float  s  = t[rr] + b4v;
                    const float  wm = s * (1.0f / (rv.w + 1e-12f));
                    wacc0 = fmaf(wm, rv.x, wacc0);
                    wacc1 = fmaf(wm, rv.y, wacc1);
                    wacc2 = fmaf(wm, rv.z, wacc2);
                }
            }
        }
    }

    // ---- full butterfly: all lanes get the query's weighted 3-vector ----
    #pragma unroll
    for (int off = 1; off < 64; off <<= 1) {
        wacc0 += __shfl_xor(wacc0, off);
        wacc1 += __shfl_xor(wacc1, off);
        wacc2 += __shfl_xor(wacc2, off);
    }

    // ---- head: 3 -> 64 -> 3 on this wave (lane = hidden unit) ----
    float th = fmaf(wacc0, W5[lane],
               fmaf(wacc1, W5[64+lane],
               fmaf(wacc2, W5[128+lane], b5[lane])));
    th = fmaxf(th, 0.f);
    float o0 = th * W6[lane*3+0];
    float o1 = th * W6[lane*3+1];
    float o2 = th * W6[lane*3+2];
    #pragma unroll
    for (int off = 1; off < 64; off <<= 1) {
        o0 += __shfl_xor(o0, off);
        o1 += __shfl_xor(o1, off);
        o2 += __shfl_xor(o2, off);
    }
    if (lane == 0) {
        out[q*3+0] = o0 + b6[0];
        out[q*3+1] = o1 + b6[1];
        out[q*3+2] = o2 + b6[2];
    }
}

extern "C" void kernel_launch(void* const* d_in, const int* in_sizes, int n_in,
                              void* d_out, int out_size, void* d_ws, size_t ws_size,
                              hipStream_t stream) {
    const float* atom_pos  = (const float*)d_in[0];
    const float* atom_feat = (const float*)d_in[1];
    const float* query_pos = (const float*)d_in[2];
    const float* W1 = (const float*)d_in[3];  const float* b1 = (const float*)d_in[4];
    const float* W2 = (const float*)d_in[5];  const float* b2 = (const float*)d_in[6];
    const float* W3 = (const float*)d_in[7];  const float* b3 = (const float*)d_in[8];
    const float* W4 = (const float*)d_in[9];  const float* b4 = (const float*)d_in[10];
    const float* W5 = (const float*)d_in[11]; const float* b5 = (const float*)d_in[12];
    const float* W6 = (const float*)d_in[13]; const float* b6 = (const float*)d_in[14];
    float* out = (float*)d_out;

    dim3 grid(4096 / WPB), block(TPB);
    hipLaunchKernelGGL(aqfn_kernel, grid, block, 0, stream,
                       atom_pos, atom_feat, query_pos,
                       W1,b1,W2,b2,W3,b3,W4,b4,W5,b5,W6,b6, out);
}

// Round 7
// 150.828 us; speedup vs baseline: 138.0991x; 1.0177x over previous
//
#include <hip/hip_runtime.h>
#include <math.h>

// AtomQueryFieldNet: NQ=4096, NA=512, pair MLP 18->64->64->32->1, cutoff mask,
// per-query 3-vector reduction, 3->64->3 head.
//
// R7: R6 structure (wave = query, ZERO barriers) with the spill fixed.
//  - R6's __launch_bounds__(256,4) made the allocator spill the 64-VGPR weight
//    fragments to scratch (VGPR=64, WRITE_SIZE 65.6MB = 64regs*64lanes*4B*4waves,
//    FETCH 26.8MB of in-loop reloads) -> latency chain ate the occupancy gain.
//  - (256,1) allocates ~100 VGPRs with zero scratch (proven in R5) -> 4 waves/SIMD;
//    LDS 39.9KB -> 4 blocks/CU -> 16 resident waves, 4 independent chains/SIMD.
//  - Everything else bit-identical to R6 (absmax 0.015625).

typedef _Float16 f16x8 __attribute__((ext_vector_type(8)));
typedef _Float16 f16x2 __attribute__((ext_vector_type(2)));
typedef float    f32x4 __attribute__((ext_vector_type(4)));

#define TPB 256
#define WPB 4     // waves (= queries) per block
#define CAP 384   // max in-range atoms per query (geometric max ~270)
#define XP  72    // exchange row pitch in f16 (144B rows, 16B-aligned)

__global__ __launch_bounds__(TPB, 1) void aqfn_kernel(
    const float* __restrict__ atom_pos,   // (512,3)
    const float* __restrict__ atom_feat,  // (512,2)
    const float* __restrict__ query_pos,  // (4096,3)
    const float* __restrict__ W1, const float* __restrict__ b1,  // (18,64),(64)
    const float* __restrict__ W2, const float* __restrict__ b2,  // (64,64),(64)
    const float* __restrict__ W3, const float* __restrict__ b3,  // (64,32),(32)
    const float* __restrict__ W4, const float* __restrict__ b4,  // (32,1),(1)
    const float* __restrict__ W5, const float* __restrict__ b5,  // (3,64),(64)
    const float* __restrict__ W6, const float* __restrict__ b6,  // (64,3),(3)
    float* __restrict__ out)              // (4096,3)
{
    __shared__ __align__(16) float4   rbuf[WPB][CAP];    // (rx,ry,rz,dist)
    __shared__ __align__(16) f16x2    fbuf[WPB][CAP];    // (f0,f1) as f16
    __shared__ __align__(16) _Float16 exch[WPB][16*XP];  // per-wave exchange

    const int tid  = threadIdx.x;
    const int wave = __builtin_amdgcn_readfirstlane(tid >> 6);
    const int lane = tid & 63;
    const int col  = lane & 15;
    const int quad = lane >> 4;
    const int q    = blockIdx.x * WPB + wave;            // wave-uniform

    // ---- per-wave weight fragment preload ----
    // B-frag layout: B[k][n]: n = col, k = quad*8 + j
    f16x8 w1f[4], w2f[2][4], w3f[2][2];
    #pragma unroll
    for (int nt = 0; nt < 4; ++nt)
        #pragma unroll
        for (int j = 0; j < 8; ++j) {
            const int k = quad*8 + j;
            w1f[nt][j] = (k < 18) ? (_Float16)W1[k*64 + nt*16 + col] : (_Float16)0.0f;
        }
    #pragma unroll
    for (int kc = 0; kc < 2; ++kc)
        #pragma unroll
        for (int nt = 0; nt < 4; ++nt)
            #pragma unroll
            for (int j = 0; j < 8; ++j)
                w2f[kc][nt][j] = (_Float16)W2[(kc*32 + quad*8 + j)*64 + nt*16 + col];
    #pragma unroll
    for (int kc = 0; kc < 2; ++kc)
        #pragma unroll
        for (int nt = 0; nt < 2; ++nt)
            #pragma unroll
            for (int j = 0; j < 8; ++j)
                w3f[kc][nt][j] = (_Float16)W3[(kc*32 + quad*8 + j)*32 + nt*16 + col];

    float b1f[4], b2f[4], b3f[2];
    #pragma unroll
    for (int nt = 0; nt < 4; ++nt) { b1f[nt] = b1[nt*16+col]; b2f[nt] = b2[nt*16+col]; }
    b3f[0] = b3[col]; b3f[1] = b3[16+col];
    const float w4a = W4[col], w4b = W4[16+col], b4v = b4[0];

    float4*    __restrict__ rb   = &rbuf[wave][0];
    f16x2*     __restrict__ fb   = &fbuf[wave][0];
    _Float16*  __restrict__ myex = &exch[wave][0];

    const float qx = query_pos[q*3+0];
    const float qy = query_pos[q*3+1];
    const float qz = query_pos[q*3+2];

    // ---- per-wave ballot compaction: atoms with dist <= 6 ----
    int count = 0;
    #pragma unroll 1
    for (int it = 0; it < 8; ++it) {
        const int a = it*64 + lane;
        const float rx = qx - atom_pos[a*3+0];
        const float ry = qy - atom_pos[a*3+1];
        const float rz = qz - atom_pos[a*3+2];
        const float ex = __fadd_rn(rx, 1e-12f);
        const float ey = __fadd_rn(ry, 1e-12f);
        const float ez = __fadd_rn(rz, 1e-12f);
        const float dd = __fadd_rn(__fadd_rn(__fmul_rn(ex,ex), __fmul_rn(ey,ey)),
                                   __fmul_rn(ez,ez));
        const float dist = sqrtf(dd);
        const bool  in   = (dist <= 6.0f);
        const unsigned long long m = __ballot(in);
        const int p = count + (int)__popcll(m & ((1ull << lane) - 1ull));
        if (in && p < CAP) {
            rb[p] = make_float4(rx, ry, rz, dist);
            fb[p] = f16x2{(_Float16)atom_feat[a*2+0], (_Float16)atom_feat[a*2+1]};
        }
        count += (int)__popcll(m);
    }
    if (count > CAP) count = CAP;   // unreachable (geometric max ~270)

    // ---- tile loop: 16 pairs/tile, one wave, no barriers ----
    float wacc0 = 0.f, wacc1 = 0.f, wacc2 = 0.f;
    const int ntiles = (count + 15) >> 4;

    #pragma unroll 1
    for (int tile = 0; tile < ntiles; ++tile) {
        const int row0 = tile << 4;
        int pr = row0 + col; if (pr >= count) pr = count - 1;
        const float4 r  = rb[pr];
        const f16x2  ff = fb[pr];
        const float dist = r.w;

        // X A-frag: A[m=col][k=quad*8+j]; x = [f0,f1,rbf(16),0...]
        f16x8 xa;
        #pragma unroll
        for (int j = 0; j < 8; ++j) {
            const int k = quad*8 + j;
            const float tt = dist - 0.4f * (float)(k - 2);   // centers linspace(0,6,16)
            float v = __expf(-10.0f * tt * tt);
            v = (k < 18) ? v : 0.0f;
            _Float16 xv = (_Float16)v;
            if (j == 0) xv = (quad == 0) ? ff[0] : xv;
            if (j == 1) xv = (quad == 0) ? ff[1] : xv;
            xa[j] = xv;
        }

        // ---- L1: 4 N-tiles, K=32 ----
        #pragma unroll
        for (int nt = 0; nt < 4; ++nt) {
            f32x4 c = {b1f[nt], b1f[nt], b1f[nt], b1f[nt]};
            c = __builtin_amdgcn_mfma_f32_16x16x32_f16(xa, w1f[nt], c, 0, 0, 0);
            #pragma unroll
            for (int rr = 0; rr < 4; ++rr)
                myex[(quad*4+rr)*XP + nt*16 + col] = (_Float16)fmaxf(c[rr], 0.0f);
        }
        f16x8 a2[2];
        #pragma unroll
        for (int kc = 0; kc < 2; ++kc)
            a2[kc] = *(const f16x8*)&myex[col*XP + kc*32 + quad*8];

        // ---- L2: 4 N-tiles x 2 K-chunks ----
        #pragma unroll
        for (int nt = 0; nt < 4; ++nt) {
            f32x4 c = {b2f[nt], b2f[nt], b2f[nt], b2f[nt]};
            c = __builtin_amdgcn_mfma_f32_16x16x32_f16(a2[0], w2f[0][nt], c, 0, 0, 0);
            c = __builtin_amdgcn_mfma_f32_16x16x32_f16(a2[1], w2f[1][nt], c, 0, 0, 0);
            #pragma unroll
            for (int rr = 0; rr < 4; ++rr)
                myex[(quad*4+rr)*XP + nt*16 + col] = (_Float16)fmaxf(c[rr], 0.0f);
        }
        f16x8 a3[2];
        #pragma unroll
        for (int kc = 0; kc < 2; ++kc)
            a3[kc] = *(const f16x8*)&myex[col*XP + kc*32 + quad*8];

        // ---- L3: 2 N-tiles x 2 K-chunks ----
        f32x4 h3[2];
        #pragma unroll
        for (int nt = 0; nt < 2; ++nt) {
            f32x4 c = {b3f[nt], b3f[nt], b3f[nt], b3f[nt]};
            c = __builtin_amdgcn_mfma_f32_16x16x32_f16(a3[0], w3f[0][nt], c, 0, 0, 0);
            h3[nt] = __builtin_amdgcn_mfma_f32_16x16x32_f16(a3[1], w3f[1][nt], c, 0, 0, 0);
        }

        // ---- L4: s[row] = sum over 32 h3 cols of relu(h3)*W4 ----
        float t[4];
        #pragma unroll
        for (int rr = 0; rr < 4; ++rr)
            t[rr] = fmaxf(h3[0][rr], 0.0f) * w4a + fmaxf(h3[1][rr], 0.0f) * w4b;
        #pragma unroll
        for (int off = 1; off < 16; off <<= 1) {
            #pragma unroll
            for (int rr = 0; rr < 4; ++rr)
                t[rr] += __shfl_xor(t[rr], off);
        }

        // ---- fused weighted accumulation: col==0 lanes own 4 pairs each ----
        if (col == 0) {
            #pragma unroll
            for (int rr = 0; rr < 4; ++rr) {
                const int p2 = row0 + quad*4 + rr;
                if (p2 < count) {
                    const float4 rv = rb[p2];
                    const float  s  = t[rr] + b4v;
                    const float  wm = s * (1.0f / (rv.w + 1e-12f));
                    wacc0 = fmaf(wm, rv.x, wacc0);
                    wacc1 = fmaf(wm, rv.y, wacc1);
                    wacc2 = fmaf(wm, rv.z, wacc2);
                }
            }
        }
    }

    // ---- full butterfly: all lanes get the query's weighted 3-vector ----
    #pragma unroll
    for (int off = 1; off < 64; off <<= 1) {
        wacc0 += __shfl_xor(wacc0, off);
        wacc1 += __shfl_xor(wacc1, off);
        wacc2 += __shfl_xor(wacc2, off);
    }

    // ---- head: 3 -> 64 -> 3 on this wave (lane = hidden unit) ----
    float th = fmaf(wacc0, W5[lane],
               fmaf(wacc1, W5[64+lane],
               fmaf(wacc2, W5[128+lane], b5[lane])));
    th = fmaxf(th, 0.f);
    float o0 = th * W6[lane*3+0];
    float o1 = th * W6[lane*3+1];
    float o2 = th * W6[lane*3+2];
    #pragma unroll
    for (int off = 1; off < 64; off <<= 1) {
        o0 += __shfl_xor(o0, off);
        o1 += __shfl_xor(o1, off);
        o2 += __shfl_xor(o2, off);
    }
    if (lane == 0) {
        out[q*3+0] = o0 + b6[0];
        out[q*3+1] = o1 + b6[1];
        out[q*3+2] = o2 + b6[2];
    }
}

extern "C" void kernel_launch(void* const* d_in, const int* in_sizes, int n_in,
                              void* d_out, int out_size, void* d_ws, size_t ws_size,
                              hipStream_t stream) {
    const float* atom_pos  = (const float*)d_in[0];
    const float* atom_feat = (const float*)d_in[1];
    const float* query_pos = (const float*)d_in[2];
    const float* W1 = (const float*)d_in[3];  const float* b1 = (const float*)d_in[4];
    const float* W2 = (const float*)d_in[5];  const float* b2 = (const float*)d_in[6];
    const float* W3 = (const float*)d_in[7];  const float* b3 = (const float*)d_in[8];
    const float* W4 = (const float*)d_in[9];  const float* b4 = (const float*)d_in[10];
    const float* W5 = (const float*)d_in[11]; const float* b5 = (const float*)d_in[12];
    const float* W6 = (const float*)d_in[13]; const float* b6 = (const float*)d_in[14];
    float* out = (float*)d_out;

    dim3 grid(4096 / WPB), block(TPB);
    hipLaunchKernelGGL(aqfn_kernel, grid, block, 0, stream,
                       atom_pos, atom_feat, query_pos,
                       W1,b1,W2,b2,W3,b3,W4,b4,W5,b5,W6,b6, out);
}

// Round 8
// 136.552 us; speedup vs baseline: 152.5365x; 1.1045x over previous
//
#include <hip/hip_runtime.h>
#include <math.h>

// AtomQueryFieldNet: NQ=4096, NA=512, pair MLP 18->64->64->32->1, cutoff mask,
// per-query 3-vector reduction, 3->64->3 head.
//
// R8: wave = query = block (grid 4096 x 64 threads), 2-tile interleave, no L4 shuffle.
//  - R5/R6/R7 all ~77-85us: per-tile serial chain (2 LDS round-trips + 16-shfl
//    reduce) with no saturated pipe. Fixes:
//    (1) L4 reduce eliminated: out = sum_p s_p*dir_p is linear in s, so lanes
//        accumulate partial t[rr]*unit_dir directly; b4 term = b4*sum(dir) (x0.25
//        for 4-quad duplication).
//    (2) two 16-pair tiles interleaved per iteration (dual exchange buffers):
//        tile B's issue hides tile A's LDS write->read latency.
//    (3) 1-wave blocks + 11.6KB LDS -> ~13 blocks/CU with backfill (R7's grid
//        of 1024 = 4 blocks/CU with no refill drained early on short queries).
//    (4) v_rcp approx instead of IEEE divide (1e-7 err vs 1.5e-2 slack).
//  - MFMA math identical to R5-R7 (fp16 in, fp32 accum; verified absmax 0.0156).

typedef _Float16 f16x8 __attribute__((ext_vector_type(8)));
typedef _Float16 f16x2 __attribute__((ext_vector_type(2)));
typedef float    f32x4 __attribute__((ext_vector_type(4)));

#define CAP 352   // max in-range atoms/query: mean@center 268, sigma 11.3 -> 7.4 sigma
#define XP  72    // exchange row pitch in f16 (144B rows, 16B-aligned)

__global__ __launch_bounds__(64, 1) void aqfn_kernel(
    const float* __restrict__ atom_pos,   // (512,3)
    const float* __restrict__ atom_feat,  // (512,2)
    const float* __restrict__ query_pos,  // (4096,3)
    const float* __restrict__ W1, const float* __restrict__ b1,  // (18,64),(64)
    const float* __restrict__ W2, const float* __restrict__ b2,  // (64,64),(64)
    const float* __restrict__ W3, const float* __restrict__ b3,  // (64,32),(32)
    const float* __restrict__ W4, const float* __restrict__ b4,  // (32,1),(1)
    const float* __restrict__ W5, const float* __restrict__ b5,  // (3,64),(64)
    const float* __restrict__ W6, const float* __restrict__ b6,  // (64,3),(3)
    float* __restrict__ out)              // (4096,3)
{
    __shared__ __align__(16) float4   rbuf[CAP];        // (rx,ry,rz,dist)
    __shared__ __align__(16) f16x2    fbuf[CAP];        // (f0,f1) as f16
    __shared__ __align__(16) _Float16 exch[2][16*XP];   // dual exchange buffers

    const int lane = threadIdx.x & 63;
    const int col  = lane & 15;
    const int quad = lane >> 4;
    const int q    = blockIdx.x;

    // ---- weight fragment preload (B-frag: B[k=quad*8+j][n=col]) ----
    f16x8 w1f[4], w2f[2][4], w3f[2][2];
    #pragma unroll
    for (int nt = 0; nt < 4; ++nt)
        #pragma unroll
        for (int j = 0; j < 8; ++j) {
            const int k = quad*8 + j;
            w1f[nt][j] = (k < 18) ? (_Float16)W1[k*64 + nt*16 + col] : (_Float16)0.0f;
        }
    #pragma unroll
    for (int kc = 0; kc < 2; ++kc)
        #pragma unroll
        for (int nt = 0; nt < 4; ++nt)
            #pragma unroll
            for (int j = 0; j < 8; ++j)
                w2f[kc][nt][j] = (_Float16)W2[(kc*32 + quad*8 + j)*64 + nt*16 + col];
    #pragma unroll
    for (int kc = 0; kc < 2; ++kc)
        #pragma unroll
        for (int nt = 0; nt < 2; ++nt)
            #pragma unroll
            for (int j = 0; j < 8; ++j)
                w3f[kc][nt][j] = (_Float16)W3[(kc*32 + quad*8 + j)*32 + nt*16 + col];

    float b1f[4], b2f[4], b3f[2];
    #pragma unroll
    for (int nt = 0; nt < 4; ++nt) { b1f[nt] = b1[nt*16+col]; b2f[nt] = b2[nt*16+col]; }
    b3f[0] = b3[col]; b3f[1] = b3[16+col];
    const float w4a = W4[col], w4b = W4[16+col], b4v = b4[0];

    const float qx = query_pos[q*3+0];
    const float qy = query_pos[q*3+1];
    const float qz = query_pos[q*3+2];

    // ---- per-wave ballot compaction: atoms with dist <= 6 ----
    int count = 0;
    #pragma unroll 1
    for (int it = 0; it < 8; ++it) {
        const int a = it*64 + lane;
        const float rx = qx - atom_pos[a*3+0];
        const float ry = qy - atom_pos[a*3+1];
        const float rz = qz - atom_pos[a*3+2];
        const float ex = __fadd_rn(rx, 1e-12f);
        const float ey = __fadd_rn(ry, 1e-12f);
        const float ez = __fadd_rn(rz, 1e-12f);
        const float dd = __fadd_rn(__fadd_rn(__fmul_rn(ex,ex), __fmul_rn(ey,ey)),
                                   __fmul_rn(ez,ez));
        const float dist = sqrtf(dd);
        const bool  in   = (dist <= 6.0f);
        const unsigned long long m = __ballot(in);
        const int p = count + (int)__popcll(m & ((1ull << lane) - 1ull));
        if (in && p < CAP) {
            rbuf[p] = make_float4(rx, ry, rz, dist);
            fbuf[p] = f16x2{(_Float16)atom_feat[a*2+0], (_Float16)atom_feat[a*2+1]};
        }
        count += (int)__popcll(m);
    }
    if (count > CAP) count = CAP;   // unreachable

    float wacc0 = 0.f, wacc1 = 0.f, wacc2 = 0.f;   // sum t_partial * unit_dir
    float dacc0 = 0.f, dacc1 = 0.f, dacc2 = 0.f;   // sum unit_dir (x4 duplicated)
    const int nsteps = (count + 31) >> 5;

    #pragma unroll 1
    for (int step = 0; step < nsteps; ++step) {
        const int row0 = step << 5;   // tile u covers pairs [row0+u*16, +16)

        float4 rv[2]; f16x2 ffv[2];
        #pragma unroll
        for (int u = 0; u < 2; ++u) {
            int pr = row0 + u*16 + col;
            if (pr >= count) pr = count - 1;
            rv[u]  = rbuf[pr];
            ffv[u] = fbuf[pr];
        }

        // X A-frags: A[m=col][k=quad*8+j]; x = [f0,f1,rbf(16),0...]
        f16x8 xa[2];
        #pragma unroll
        for (int u = 0; u < 2; ++u) {
            const float dist = rv[u].w;
            #pragma unroll
            for (int j = 0; j < 8; ++j) {
                const int k = quad*8 + j;
                const float tt = dist - 0.4f * (float)(k - 2);  // centers linspace(0,6,16)
                float v = __expf(-10.0f * tt * tt);
                v = (k < 18) ? v : 0.0f;
                _Float16 xv = (_Float16)v;
                if (j == 0) xv = (quad == 0) ? ffv[u][0] : xv;
                if (j == 1) xv = (quad == 0) ? ffv[u][1] : xv;
                xa[u][j] = xv;
            }
        }

        // ---- L1: both tiles ----
        #pragma unroll
        for (int u = 0; u < 2; ++u)
            #pragma unroll
            for (int nt = 0; nt < 4; ++nt) {
                f32x4 c = {b1f[nt], b1f[nt], b1f[nt], b1f[nt]};
                c = __builtin_amdgcn_mfma_f32_16x16x32_f16(xa[u], w1f[nt], c, 0, 0, 0);
                #pragma unroll
                for (int rr = 0; rr < 4; ++rr)
                    exch[u][(quad*4+rr)*XP + nt*16 + col] = (_Float16)fmaxf(c[rr], 0.0f);
            }
        f16x8 a2[2][2];
        #pragma unroll
        for (int u = 0; u < 2; ++u)
            #pragma unroll
            for (int kc = 0; kc < 2; ++kc)
                a2[u][kc] = *(const f16x8*)&exch[u][col*XP + kc*32 + quad*8];

        // ---- L2: both tiles ----
        #pragma unroll
        for (int u = 0; u < 2; ++u)
            #pragma unroll
            for (int nt = 0; nt < 4; ++nt) {
                f32x4 c = {b2f[nt], b2f[nt], b2f[nt], b2f[nt]};
                c = __builtin_amdgcn_mfma_f32_16x16x32_f16(a2[u][0], w2f[0][nt], c, 0, 0, 0);
                c = __builtin_amdgcn_mfma_f32_16x16x32_f16(a2[u][1], w2f[1][nt], c, 0, 0, 0);
                #pragma unroll
                for (int rr = 0; rr < 4; ++rr)
                    exch[u][(quad*4+rr)*XP + nt*16 + col] = (_Float16)fmaxf(c[rr], 0.0f);
            }
        f16x8 a3[2][2];
        #pragma unroll
        for (int u = 0; u < 2; ++u)
            #pragma unroll
            for (int kc = 0; kc < 2; ++kc)
                a3[u][kc] = *(const f16x8*)&exch[u][col*XP + kc*32 + quad*8];

        // ---- L3: both tiles ----
        f32x4 h3[2][2];
        #pragma unroll
        for (int u = 0; u < 2; ++u)
            #pragma unroll
            for (int nt = 0; nt < 2; ++nt) {
                f32x4 c = {b3f[nt], b3f[nt], b3f[nt], b3f[nt]};
                c = __builtin_amdgcn_mfma_f32_16x16x32_f16(a3[u][0], w3f[0][nt], c, 0, 0, 0);
                h3[u][nt] = __builtin_amdgcn_mfma_f32_16x16x32_f16(a3[u][1], w3f[1][nt], c, 0, 0, 0);
            }

        // ---- L4 partial + direct accumulation (no shuffle reduce) ----
        // lane(col,quad) holds h3 of pairs (row0+u*16+quad*4+rr), hidden {col,16+col}.
        #pragma unroll
        for (int u = 0; u < 2; ++u) {
            const int tb = row0 + u*16;
            float t4[4];
            #pragma unroll
            for (int rr = 0; rr < 4; ++rr)
                t4[rr] = fmaxf(h3[u][0][rr], 0.0f) * w4a + fmaxf(h3[u][1][rr], 0.0f) * w4b;
            #pragma unroll
            for (int rr = 0; rr < 4; ++rr) {
                int p2 = tb + quad*4 + rr;
                const bool vld = (p2 < count);
                if (!vld) p2 = count - 1;              // keep address valid
                const float4 rp  = rbuf[p2];           // quad-broadcast read
                const float  inv = __builtin_amdgcn_rcpf(rp.w + 1e-12f);
                const float  tm  = vld ? t4[rr] : 0.0f;
                wacc0 = fmaf(tm, rp.x * inv, wacc0);
                wacc1 = fmaf(tm, rp.y * inv, wacc1);
                wacc2 = fmaf(tm, rp.z * inv, wacc2);
            }
            // b4 * sum(unit_dir): pair (tb+col) duplicated on 4 quads -> x0.25 later
            const bool vd  = (tb + col) < count;
            const float di = __builtin_amdgcn_rcpf(rv[u].w + 1e-12f);
            const float dm = vd ? di : 0.0f;
            dacc0 = fmaf(dm, rv[u].x, dacc0);
            dacc1 = fmaf(dm, rv[u].y, dacc1);
            dacc2 = fmaf(dm, rv[u].z, dacc2);
        }
    }

    // fold b4 term (0.25: each pair's dir was accumulated once per quad)
    const float b4s = b4v * 0.25f;
    wacc0 = fmaf(b4s, dacc0, wacc0);
    wacc1 = fmaf(b4s, dacc1, wacc1);
    wacc2 = fmaf(b4s, dacc2, wacc2);

    // ---- 64-lane butterfly: all lanes get the query's weighted 3-vector ----
    #pragma unroll
    for (int off = 1; off < 64; off <<= 1) {
        wacc0 += __shfl_xor(wacc0, off);
        wacc1 += __shfl_xor(wacc1, off);
        wacc2 += __shfl_xor(wacc2, off);
    }

    // ---- head: 3 -> 64 -> 3 (lane = hidden unit) ----
    float th = fmaf(wacc0, W5[lane],
               fmaf(wacc1, W5[64+lane],
               fmaf(wacc2, W5[128+lane], b5[lane])));
    th = fmaxf(th, 0.f);
    float o0 = th * W6[lane*3+0];
    float o1 = th * W6[lane*3+1];
    float o2 = th * W6[lane*3+2];
    #pragma unroll
    for (int off = 1; off < 64; off <<= 1) {
        o0 += __shfl_xor(o0, off);
        o1 += __shfl_xor(o1, off);
        o2 += __shfl_xor(o2, off);
    }
    if (lane == 0) {
        out[q*3+0] = o0 + b6[0];
        out[q*3+1] = o1 + b6[1];
        out[q*3+2] = o2 + b6[2];
    }
}

extern "C" void kernel_launch(void* const* d_in, const int* in_sizes, int n_in,
                              void* d_out, int out_size, void* d_ws, size_t ws_size,
                              hipStream_t stream) {
    const float* atom_pos  = (const float*)d_in[0];
    const float* atom_feat = (const float*)d_in[1];
    const float* query_pos = (const float*)d_in[2];
    const float* W1 = (const float*)d_in[3];  const float* b1 = (const float*)d_in[4];
    const float* W2 = (const float*)d_in[5];  const float* b2 = (const float*)d_in[6];
    const float* W3 = (const float*)d_in[7];  const float* b3 = (const float*)d_in[8];
    const float* W4 = (const float*)d_in[9];  const float* b4 = (const float*)d_in[10];
    const float* W5 = (const float*)d_in[11]; const float* b5 = (const float*)d_in[12];
    const float* W6 = (const float*)d_in[13]; const float* b6 = (const float*)d_in[14];
    float* out = (float*)d_out;

    dim3 grid(4096), block(64);
    hipLaunchKernelGGL(aqfn_kernel, grid, block, 0, stream,
                       atom_pos, atom_feat, query_pos,
                       W1,b1,W2,b2,W3,b3,W4,b4,W5,b5,W6,b6, out);
}

// Round 9
// 122.205 us; speedup vs baseline: 170.4444x; 1.1174x over previous
//
#include <hip/hip_runtime.h>
#include <math.h>

// AtomQueryFieldNet: NQ=4096, NA=512, pair MLP 18->64->64->32->1, cutoff mask,
// per-query 3-vector reduction, 3->64->3 head.
//
// R9: transposed MFMA chain (h^T = W^T @ X^T) + weight-repack pre-kernel.
//  - Swapping mfma operand order gives transposed outputs where each lane holds
//    4 CONTIGUOUS hidden units of its own pair -> inter-layer exchange is
//    4x ds_write_b64 + 2x ds_read_b128 per layer (vs 16x ds_write_b16 + 2 reads).
//    DS ops/tile: 36 -> 12, round-trip chains 3x shorter.
//  - L4: 2x shfl_xor quad-reduce gives every lane its pair's full s -> weighted
//    accumulation uses registers (rv), no rbuf re-reads, b4 added exactly.
//    All 4 quads accumulate the same pair -> final scale 0.25 after butterfly.
//  - b1 folded into W1 row k=18 (X[18]=1): no L1 bias registers.
//  - repack_kernel (runs every call) writes MFMA-fragment-ordered weights to
//    d_ws: main wave preload = 24 coalesced dwordx4 loads (was ~160 scalar).
//  - MFMA math otherwise identical to R5-R8 (fp16 in, fp32 accum, RNE casts).

typedef _Float16 f16x8 __attribute__((ext_vector_type(8)));
typedef _Float16 f16x4 __attribute__((ext_vector_type(4)));
typedef _Float16 f16x2 __attribute__((ext_vector_type(2)));
typedef float    f32x4 __attribute__((ext_vector_type(4)));

#define CAP 352   // max in-range atoms/query (geometric max ~270, +7 sigma)
#define XP2 72    // exchange row pitch in f16 (144B rows; b64/b128 aligned)

// ---- repack: weights -> MFMA fragment order in d_ws ----
// f16 frags (16 chunks x 64 lanes x 16B = 16KB):
//   chunk 0..3   : w1f[mt]      elem j: W1aug[quad*8+j][mt*16+col] (k==18 -> b1)
//   chunk 4..11  : w2f[kc][mt]  (chunk=4+kc*4+mt): W2[kc*32+quad*8+j][mt*16+col]
//   chunk 12..15 : w3f[kc][mt]  (chunk=12+kc*2+mt): W3[kc*32+quad*8+j][mt*16+col]
// f32 bias chunks at +16KB (8 chunks x 64 lanes x 16B = 4KB... stored as float4):
//   chunk 0..3: b2v[mt][rr]=b2[mt*16+quad*4+rr]; 4..5: b3v; 6..7: w4v
__global__ __launch_bounds__(64) void repack_kernel(
    const float* __restrict__ W1, const float* __restrict__ b1,
    const float* __restrict__ W2, const float* __restrict__ b2,
    const float* __restrict__ W3, const float* __restrict__ b3,
    const float* __restrict__ W4, char* __restrict__ ws)
{
    const int b = blockIdx.x, l = threadIdx.x;
    const int col = l & 15, quad = l >> 4;
    if (b < 16) {
        f16x8 v;
        #pragma unroll
        for (int j = 0; j < 8; ++j) {
            const int k = quad*8 + j;
            float x;
            if (b < 4) {
                const int mt = b;
                x = (k < 18) ? W1[k*64 + mt*16 + col]
                             : (k == 18 ? b1[mt*16 + col] : 0.0f);
            } else if (b < 12) {
                const int kc = (b-4) >> 2, mt = (b-4) & 3;
                x = W2[(kc*32 + k)*64 + mt*16 + col];
            } else {
                const int kc = (b-12) >> 1, mt = (b-12) & 1;
                x = W3[(kc*32 + k)*32 + mt*16 + col];
            }
            v[j] = (_Float16)x;
        }
        *(f16x8*)(ws + (b*64 + l)*16) = v;
    } else {
        const int d = b - 16;
        float o[4];
        #pragma unroll
        for (int rr = 0; rr < 4; ++rr) {
            const int idx = quad*4 + rr;
            if (d < 4)      o[rr] = b2[d*16 + idx];
            else if (d < 6) o[rr] = b3[(d-4)*16 + idx];
            else            o[rr] = W4[(d-6)*16 + idx];
        }
        *(float4*)(ws + 16384 + (d*64 + l)*16) = make_float4(o[0],o[1],o[2],o[3]);
    }
}

__global__ __launch_bounds__(64, 1) void aqfn_kernel(
    const float* __restrict__ atom_pos,   // (512,3)
    const float* __restrict__ atom_feat,  // (512,2)
    const float* __restrict__ query_pos,  // (4096,3)
    const float* __restrict__ b4,         // (1)
    const float* __restrict__ W5, const float* __restrict__ b5,  // (3,64),(64)
    const float* __restrict__ W6, const float* __restrict__ b6,  // (64,3),(3)
    const char*  __restrict__ ws,         // repacked weights
    float* __restrict__ out)              // (4096,3)
{
    __shared__ __align__(16) float4   rbuf[CAP];        // (rx,ry,rz,dist)
    __shared__ __align__(16) f16x2    fbuf[CAP];        // (f0,f1) as f16
    __shared__ __align__(16) _Float16 exch[2][16*XP2];  // dual exchange buffers

    const int lane = threadIdx.x & 63;
    const int col  = lane & 15;
    const int quad = lane >> 4;
    const int q    = blockIdx.x;

    // ---- fragment preload: 24 coalesced dwordx4 loads ----
    const f16x8*  wsf = (const f16x8*)ws;
    const float4* wsb = (const float4*)(ws + 16384);
    f16x8 w1f[4], w2f[2][4], w3f[2][2];
    #pragma unroll
    for (int mt = 0; mt < 4; ++mt) w1f[mt] = wsf[mt*64 + lane];
    #pragma unroll
    for (int kc = 0; kc < 2; ++kc)
        #pragma unroll
        for (int mt = 0; mt < 4; ++mt) w2f[kc][mt] = wsf[(4 + kc*4 + mt)*64 + lane];
    #pragma unroll
    for (int kc = 0; kc < 2; ++kc)
        #pragma unroll
        for (int mt = 0; mt < 2; ++mt) w3f[kc][mt] = wsf[(12 + kc*2 + mt)*64 + lane];
    float4 b2v[4], b3v[2], w4v[2];
    #pragma unroll
    for (int mt = 0; mt < 4; ++mt) b2v[mt] = wsb[mt*64 + lane];
    #pragma unroll
    for (int mt = 0; mt < 2; ++mt) { b3v[mt] = wsb[(4+mt)*64 + lane];
                                     w4v[mt] = wsb[(6+mt)*64 + lane]; }
    const float b4v = b4[0];

    const float qx = query_pos[q*3+0];
    const float qy = query_pos[q*3+1];
    const float qz = query_pos[q*3+2];

    // ---- per-wave ballot compaction: atoms with dist <= 6 ----
    int count = 0;
    #pragma unroll 1
    for (int it = 0; it < 8; ++it) {
        const int a = it*64 + lane;
        const float rx = qx - atom_pos[a*3+0];
        const float ry = qy - atom_pos[a*3+1];
        const float rz = qz - atom_pos[a*3+2];
        const float ex = __fadd_rn(rx, 1e-12f);
        const float ey = __fadd_rn(ry, 1e-12f);
        const float ez = __fadd_rn(rz, 1e-12f);
        const float dd = __fadd_rn(__fadd_rn(__fmul_rn(ex,ex), __fmul_rn(ey,ey)),
                                   __fmul_rn(ez,ez));
        const float dist = sqrtf(dd);
        const bool  in   = (dist <= 6.0f);
        const unsigned long long m = __ballot(in);
        const int p = count + (int)__popcll(m & ((1ull << lane) - 1ull));
        if (in && p < CAP) {
            rbuf[p] = make_float4(rx, ry, rz, dist);
            fbuf[p] = f16x2{(_Float16)atom_feat[a*2+0], (_Float16)atom_feat[a*2+1]};
        }
        count += (int)__popcll(m);
    }
    if (count > CAP) count = CAP;   // unreachable

    float wacc0 = 0.f, wacc1 = 0.f, wacc2 = 0.f;
    const int nsteps = (count + 31) >> 5;

    #pragma unroll 1
    for (int step = 0; step < nsteps; ++step) {
        const int row0 = step << 5;

        float4 rv[2]; f16x2 ffv[2];
        #pragma unroll
        for (int u = 0; u < 2; ++u) {
            int pr = row0 + u*16 + col;
            if (pr >= count) pr = count - 1;
            rv[u]  = rbuf[pr];
            ffv[u] = fbuf[pr];
        }

        // X B-frags: B[k=quad*8+j][n=col]; x = [f0,f1,rbf(16),1(bias),0...]
        f16x8 xa[2];
        #pragma unroll
        for (int u = 0; u < 2; ++u) {
            const float dist = rv[u].w;
            #pragma unroll
            for (int j = 0; j < 8; ++j) {
                const int k = quad*8 + j;
                const float tt = dist - 0.4f * (float)(k - 2);  // centers linspace(0,6,16)
                float v = __expf(-10.0f * tt * tt);
                v = (k < 18) ? v : 0.0f;
                _Float16 xv = (_Float16)v;
                if (k == 18) xv = (_Float16)1.0f;      // bias slot
                if (j == 0) xv = (quad == 0) ? ffv[u][0] : xv;
                if (j == 1) xv = (quad == 0) ? ffv[u][1] : xv;
                xa[u][j] = xv;
            }
        }

        // ---- L1 transposed: h1^T[mt*16+quad*4+rr][pair=col] ----
        #pragma unroll
        for (int u = 0; u < 2; ++u)
            #pragma unroll
            for (int mt = 0; mt < 4; ++mt) {
                f32x4 c = {0.f, 0.f, 0.f, 0.f};
                c = __builtin_amdgcn_mfma_f32_16x16x32_f16(w1f[mt], xa[u], c, 0, 0, 0);
                f16x4 p = {(_Float16)fmaxf(c[0],0.f), (_Float16)fmaxf(c[1],0.f),
                           (_Float16)fmaxf(c[2],0.f), (_Float16)fmaxf(c[3],0.f)};
                *(f16x4*)&exch[u][col*XP2 + mt*16 + quad*4] = p;
            }
        f16x8 a2[2][2];
        #pragma unroll
        for (int u = 0; u < 2; ++u)
            #pragma unroll
            for (int kc = 0; kc < 2; ++kc)
                a2[u][kc] = *(const f16x8*)&exch[u][col*XP2 + kc*32 + quad*8];

        // ---- L2 transposed ----
        #pragma unroll
        for (int u = 0; u < 2; ++u)
            #pragma unroll
            for (int mt = 0; mt < 4; ++mt) {
                f32x4 c = {b2v[mt].x, b2v[mt].y, b2v[mt].z, b2v[mt].w};
                c = __builtin_amdgcn_mfma_f32_16x16x32_f16(w2f[0][mt], a2[u][0], c, 0, 0, 0);
                c = __builtin_amdgcn_mfma_f32_16x16x32_f16(w2f[1][mt], a2[u][1], c, 0, 0, 0);
                f16x4 p = {(_Float16)fmaxf(c[0],0.f), (_Float16)fmaxf(c[1],0.f),
                           (_Float16)fmaxf(c[2],0.f), (_Float16)fmaxf(c[3],0.f)};
                *(f16x4*)&exch[u][col*XP2 + mt*16 + quad*4] = p;
            }
        f16x8 a3[2][2];
        #pragma unroll
        for (int u = 0; u < 2; ++u)
            #pragma unroll
            for (int kc = 0; kc < 2; ++kc)
                a3[u][kc] = *(const f16x8*)&exch[u][col*XP2 + kc*32 + quad*8];

        // ---- L3 transposed + L4 partial + quad-reduce + fused accumulation ----
        #pragma unroll
        for (int u = 0; u < 2; ++u) {
            float s = 0.f;
            #pragma unroll
            for (int mt = 0; mt < 2; ++mt) {
                f32x4 c = {b3v[mt].x, b3v[mt].y, b3v[mt].z, b3v[mt].w};
                c = __builtin_amdgcn_mfma_f32_16x16x32_f16(w3f[0][mt], a3[u][0], c, 0, 0, 0);
                c = __builtin_amdgcn_mfma_f32_16x16x32_f16(w3f[1][mt], a3[u][1], c, 0, 0, 0);
                const float* wv = &w4v[mt].x;
                #pragma unroll
                for (int rr = 0; rr < 4; ++rr)
                    s = fmaf(fmaxf(c[rr], 0.f), wv[rr], s);
            }
            // sum over the 4 quads holding this pair's 32 h3 values
            s += __shfl_xor(s, 16);
            s += __shfl_xor(s, 32);
            s += b4v;
            const int  p2  = row0 + u*16 + col;
            const bool vld = (p2 < count);
            const float inv = __builtin_amdgcn_rcpf(rv[u].w + 1e-12f);
            const float wm  = vld ? (s * inv) : 0.f;
            wacc0 = fmaf(wm, rv[u].x, wacc0);
            wacc1 = fmaf(wm, rv[u].y, wacc1);
            wacc2 = fmaf(wm, rv[u].z, wacc2);
        }
    }

    // ---- 64-lane butterfly; each pair was accumulated by all 4 quads -> x0.25 ----
    #pragma unroll
    for (int off = 1; off < 64; off <<= 1) {
        wacc0 += __shfl_xor(wacc0, off);
        wacc1 += __shfl_xor(wacc1, off);
        wacc2 += __shfl_xor(wacc2, off);
    }
    wacc0 *= 0.25f; wacc1 *= 0.25f; wacc2 *= 0.25f;

    // ---- head: 3 -> 64 -> 3 (lane = hidden unit) ----
    float th = fmaf(wacc0, W5[lane],
               fmaf(wacc1, W5[64+lane],
               fmaf(wacc2, W5[128+lane], b5[lane])));
    th = fmaxf(th, 0.f);
    float o0 = th * W6[lane*3+0];
    float o1 = th * W6[lane*3+1];
    float o2 = th * W6[lane*3+2];
    #pragma unroll
    for (int off = 1; off < 64; off <<= 1) {
        o0 += __shfl_xor(o0, off);
        o1 += __shfl_xor(o1, off);
        o2 += __shfl_xor(o2, off);
    }
    if (lane == 0) {
        out[q*3+0] = o0 + b6[0];
        out[q*3+1] = o1 + b6[1];
        out[q*3+2] = o2 + b6[2];
    }
}

extern "C" void kernel_launch(void* const* d_in, const int* in_sizes, int n_in,
                              void* d_out, int out_size, void* d_ws, size_t ws_size,
                              hipStream_t stream) {
    const float* atom_pos  = (const float*)d_in[0];
    const float* atom_feat = (const float*)d_in[1];
    const float* query_pos = (const float*)d_in[2];
    const float* W1 = (const float*)d_in[3];  const float* b1 = (const float*)d_in[4];
    const float* W2 = (const float*)d_in[5];  const float* b2 = (const float*)d_in[6];
    const float* W3 = (const float*)d_in[7];  const float* b3 = (const float*)d_in[8];
    const float* W4 = (const float*)d_in[9];  const float* b4 = (const float*)d_in[10];
    const float* W5 = (const float*)d_in[11]; const float* b5 = (const float*)d_in[12];
    const float* W6 = (const float*)d_in[13]; const float* b6 = (const float*)d_in[14];
    float* out = (float*)d_out;
    char*  ws  = (char*)d_ws;   // needs 16KB frags + 8KB biases = 24KB

    hipLaunchKernelGGL(repack_kernel, dim3(24), dim3(64), 0, stream,
                       W1, b1, W2, b2, W3, b3, W4, ws);
    hipLaunchKernelGGL(aqfn_kernel, dim3(4096), dim3(64), 0, stream,
                       atom_pos, atom_feat, query_pos, b4, W5, b5, W6, b6,
                       (const char*)ws, out);
}